// Round 2
// baseline (1376.583 us; speedup 1.0000x reference)
//
#include <hip/hip_runtime.h>
#include <hip/hip_bf16.h>
#include <stdint.h>

typedef unsigned short u16;
typedef __attribute__((ext_vector_type(8))) short bf16x8;   // 8 bf16 = 4 VGPRs
typedef __attribute__((ext_vector_type(4))) float f32x4;

#define BATCH 8
#define SEQ   1024
#define FDIM  1024
#define NHEAD 16
#define DHEAD 64

__device__ __forceinline__ float bf2f(u16 u) {
  union { unsigned int i; float f; } v; v.i = ((unsigned int)u) << 16; return v.f;
}
__device__ __forceinline__ u16 f2bf(float f) {
  union { float f; unsigned int i; } v; v.f = f;
  unsigned int x = v.i;
  return (u16)((x + 0x7fffu + ((x >> 16) & 1u)) >> 16);  // RNE
}

// load 8 contiguous elements as 8 bf16 packed in a uint4
__device__ __forceinline__ uint4 load8(const u16* p) { return *(const uint4*)p; }
__device__ __forceinline__ uint4 load8(const float* p) {
  float4 a = *(const float4*)p;
  float4 b = *(const float4*)(p + 4);
  union { u16 h[8]; uint4 v; } r;
  r.h[0] = f2bf(a.x); r.h[1] = f2bf(a.y); r.h[2] = f2bf(a.z); r.h[3] = f2bf(a.w);
  r.h[4] = f2bf(b.x); r.h[5] = f2bf(b.y); r.h[6] = f2bf(b.z); r.h[7] = f2bf(b.w);
  return r.v;
}

// ---------- 64x64 tile transpose + fp32->bf16: dst[c][r] = src[r][c] ---------
__global__ __launch_bounds__(256) void transpose_k(
    const float* __restrict__ src, u16* __restrict__ dst, int srcLd, int dstLd) {
  __shared__ u16 t[64][72];
  const int r0 = blockIdx.y * 64, c0 = blockIdx.x * 64;
  const int tid = threadIdx.x;
  for (int p = 0; p < 16; ++p) {
    int idx = p * 256 + tid, r = idx >> 6, c = idx & 63;
    t[r][c] = f2bf(src[(long)(r0 + r) * srcLd + (c0 + c)]);
  }
  __syncthreads();
  for (int p = 0; p < 16; ++p) {
    int idx = p * 256 + tid, r = idx >> 6, c = idx & 63;
    dst[(long)(c0 + r) * dstLd + (r0 + c)] = t[c][r];
  }
}

// ------------- GEMM: C = A[MxK] * Bt[NxK]^T, bf16 MFMA, fp32 acc -------------
// A may be fp32 (converted during LDS staging) or bf16 (u16).
// MODE 0: bf16 out at ctxZ(z) + row*ldc + col   (z = b*16+h batching)
// MODE 1: f32 out at row*ldc + col
// MODE 2: bf16 out scattered to [b,h,s,d] from row=(b,s), col=(h,d)
// MODE 3: bf16 out scattered to [b,h,d,s] from row=(b,s), col=(h,d)
template<int MODE, int WGM, int WGN, int MI, int NJ, typename AT>
__global__ __launch_bounds__(256) void gemm_bt(
    const AT* __restrict__ A, const u16* __restrict__ Bt, void* __restrict__ C,
    int K, int lda, int ldb, int ldc, long aZ, long bZ) {
  constexpr int BM = WGM * MI * 16;
  constexpr int BN = WGN * NJ * 16;
  __shared__ __align__(16) u16 As[BM][40];   // 32 k + 8 pad (80B row = 16B mult)
  __shared__ __align__(16) u16 Bs[BN][40];
  const int tid = threadIdx.x;
  const int wave = tid >> 6, lane = tid & 63;
  const int quad = lane >> 4, l16 = lane & 15;
  const int wm = wave / WGN, wn = wave % WGN;
  const int m0 = blockIdx.y * BM, n0 = blockIdx.x * BN;
  const int z = blockIdx.z;
  A  += (long)z * aZ;
  Bt += (long)z * bZ;

  f32x4 acc[MI][NJ];
#pragma unroll
  for (int i = 0; i < MI; ++i)
#pragma unroll
    for (int j = 0; j < NJ; ++j) acc[i][j] = (f32x4){0.f, 0.f, 0.f, 0.f};

  const int srow = tid >> 2, scol = (tid & 3) * 8;
  for (int k0 = 0; k0 < K; k0 += 32) {
    __syncthreads();
#pragma unroll
    for (int p = 0; p < BM / 64; ++p) {
      int r = p * 64 + srow;
      *(uint4*)&As[r][scol] = load8(&A[(long)(m0 + r) * lda + k0 + scol]);
    }
#pragma unroll
    for (int p = 0; p < BN / 64; ++p) {
      int r = p * 64 + srow;
      *(uint4*)&Bs[r][scol] = load8(&Bt[(long)(n0 + r) * ldb + k0 + scol]);
    }
    __syncthreads();
    bf16x8 af[MI], bfr[NJ];
#pragma unroll
    for (int i = 0; i < MI; ++i)
      af[i] = *(const bf16x8*)&As[wm * MI * 16 + i * 16 + l16][quad * 8];
#pragma unroll
    for (int j = 0; j < NJ; ++j)
      bfr[j] = *(const bf16x8*)&Bs[wn * NJ * 16 + j * 16 + l16][quad * 8];
#pragma unroll
    for (int i = 0; i < MI; ++i)
#pragma unroll
      for (int j = 0; j < NJ; ++j)
        acc[i][j] = __builtin_amdgcn_mfma_f32_16x16x32_bf16(af[i], bfr[j], acc[i][j], 0, 0, 0);
  }

#pragma unroll
  for (int i = 0; i < MI; ++i) {
    const int rowb = m0 + wm * MI * 16 + i * 16 + quad * 4;
#pragma unroll
    for (int j = 0; j < NJ; ++j) {
      const int col = n0 + wn * NJ * 16 + j * 16 + l16;
#pragma unroll
      for (int r = 0; r < 4; ++r) {
        const float v = acc[i][j][r];
        const int row = rowb + r;
        if (MODE == 0) {
          long cz = (long)(z >> 4) * (SEQ * FDIM) + (long)(z & 15) * DHEAD;
          ((u16*)C)[cz + (long)row * ldc + col] = f2bf(v);
        } else if (MODE == 1) {
          ((float*)C)[(long)row * ldc + col] = v;
        } else if (MODE == 2) {
          int bb = row >> 10, ss = row & 1023, hh = col >> 6, dd = col & 63;
          ((u16*)C)[((long)(bb * NHEAD + hh) * SEQ + ss) * DHEAD + dd] = f2bf(v);
        } else {
          int bb = row >> 10, ss = row & 1023, hh = col >> 6, dd = col & 63;
          ((u16*)C)[((long)(bb * NHEAD + hh) * DHEAD + dd) * SEQ + ss] = f2bf(v);
        }
      }
    }
  }
}

// --------- attention: scores (QK^T/8 + mask) + softmax -> P (fp32) -----------
// grid: x = q-tile (S/64), y = head, z = batch. 4 waves, each owns 16 q rows.
__global__ __launch_bounds__(256) void attn_kernel(
    const u16* __restrict__ Qb, const u16* __restrict__ Kb,
    const float* __restrict__ Msk, float* __restrict__ P) {
  __shared__ __align__(16) u16 Qs[64][72];
  __shared__ __align__(16) u16 Ks[64][72];
  const int tid = threadIdx.x, wave = tid >> 6, lane = tid & 63;
  const int quad = lane >> 4, l16 = lane & 15;
  const int q0 = blockIdx.x * 64, h = blockIdx.y, b = blockIdx.z;
  const long bh = (long)b * NHEAD + h;
  const u16* Qp = Qb + bh * SEQ * DHEAD + (long)q0 * DHEAD;
  const u16* Kp = Kb + bh * SEQ * DHEAD;
  const float* Mp = Msk + ((long)b * SEQ + q0) * SEQ;
  float* Pp = P + bh * (long)SEQ * SEQ + (long)q0 * SEQ;

  {
    int r = tid >> 3, c = (tid & 7) * 8;
    *(uint4*)&Qs[r][c]      = *(const uint4*)&Qp[r * DHEAD + c];
    *(uint4*)&Qs[r + 32][c] = *(const uint4*)&Qp[(r + 32) * DHEAD + c];
  }
  __syncthreads();
  const bf16x8 aq0 = *(const bf16x8*)&Qs[wave * 16 + l16][quad * 8];
  const bf16x8 aq1 = *(const bf16x8*)&Qs[wave * 16 + l16][32 + quad * 8];

  float m[4], l[4], rl[4];
#pragma unroll
  for (int r = 0; r < 4; ++r) { m[r] = -3.0e38f; l[r] = 0.f; rl[r] = 0.f; }

  for (int pass = 0; pass < 2; ++pass) {
    for (int st = 0; st < SEQ / 64; ++st) {
      const int sk0 = st * 64;
      __syncthreads();
      {
        int r = tid >> 3, c = (tid & 7) * 8;
        *(uint4*)&Ks[r][c]      = *(const uint4*)&Kp[(sk0 + r) * DHEAD + c];
        *(uint4*)&Ks[r + 32][c] = *(const uint4*)&Kp[(sk0 + r + 32) * DHEAD + c];
      }
      __syncthreads();
      float sv[4][4];
#pragma unroll
      for (int j = 0; j < 4; ++j) {
        bf16x8 bk0 = *(const bf16x8*)&Ks[j * 16 + l16][quad * 8];
        bf16x8 bk1 = *(const bf16x8*)&Ks[j * 16 + l16][32 + quad * 8];
        f32x4 sc = (f32x4){0.f, 0.f, 0.f, 0.f};
        sc = __builtin_amdgcn_mfma_f32_16x16x32_bf16(aq0, bk0, sc, 0, 0, 0);
        sc = __builtin_amdgcn_mfma_f32_16x16x32_bf16(aq1, bk1, sc, 0, 0, 0);
#pragma unroll
        for (int r = 0; r < 4; ++r) {
          int qr = wave * 16 + quad * 4 + r;
          float mk = Mp[(long)qr * SEQ + sk0 + j * 16 + l16];
          sv[j][r] = sc[r] * 0.125f + (mk - 1.0f) * 1.0e9f;
        }
      }
      if (pass == 0) {
#pragma unroll
        for (int r = 0; r < 4; ++r) {
          float tm = fmaxf(fmaxf(sv[0][r], sv[1][r]), fmaxf(sv[2][r], sv[3][r]));
#pragma unroll
          for (int off = 1; off < 16; off <<= 1) tm = fmaxf(tm, __shfl_xor(tm, off, 64));
          float mn = fmaxf(m[r], tm);
          float ps = __expf(sv[0][r] - mn) + __expf(sv[1][r] - mn) +
                     __expf(sv[2][r] - mn) + __expf(sv[3][r] - mn);
#pragma unroll
          for (int off = 1; off < 16; off <<= 1) ps += __shfl_xor(ps, off, 64);
          l[r] = l[r] * __expf(m[r] - mn) + ps;
          m[r] = mn;
        }
      } else {
#pragma unroll
        for (int j = 0; j < 4; ++j)
#pragma unroll
          for (int r = 0; r < 4; ++r) {
            int qr = wave * 16 + quad * 4 + r;
            Pp[(long)qr * SEQ + sk0 + j * 16 + l16] = __expf(sv[j][r] - m[r]) * rl[r];
          }
      }
    }
    if (pass == 0) {
#pragma unroll
      for (int r = 0; r < 4; ++r) rl[r] = 1.0f / l[r];
    }
  }
}

// --------------- residual + LayerNorm (weight=1, bias=0) ---------------------
__global__ __launch_bounds__(256) void ln_kernel(
    const float* __restrict__ O, const float* __restrict__ Xq, float* __restrict__ out) {
  const int row = blockIdx.x, tid = threadIdx.x;
  const float4 o = *(const float4*)&O[(long)row * FDIM + tid * 4];
  const float4 q = *(const float4*)&Xq[(long)row * FDIM + tid * 4];
  float x[4] = { o.x + q.x, o.y + q.y, o.z + q.z, o.w + q.w };
  float s  = x[0] + x[1] + x[2] + x[3];
  float s2 = x[0]*x[0] + x[1]*x[1] + x[2]*x[2] + x[3]*x[3];
#pragma unroll
  for (int off = 32; off; off >>= 1) {
    s  += __shfl_xor(s, off, 64);
    s2 += __shfl_xor(s2, off, 64);
  }
  __shared__ float red[8];
  const int wave = tid >> 6, lane = tid & 63;
  if (lane == 0) { red[wave] = s; red[4 + wave] = s2; }
  __syncthreads();
  s  = red[0] + red[1] + red[2] + red[3];
  s2 = red[4] + red[5] + red[6] + red[7];
  const float mu = s * (1.0f / FDIM);
  const float var = s2 * (1.0f / FDIM) - mu * mu;
  const float rs = rsqrtf(var + 1e-5f);
  float4 res;
  res.x = (x[0] - mu) * rs; res.y = (x[1] - mu) * rs;
  res.z = (x[2] - mu) * rs; res.w = (x[3] - mu) * rs;
  *(float4*)&out[(long)row * FDIM + tid * 4] = res;
}

extern "C" void kernel_launch(void* const* d_in, const int* in_sizes, int n_in,
                              void* d_out, int out_size, void* d_ws, size_t ws_size,
                              hipStream_t stream) {
  const float* Xq = (const float*)d_in[0];
  const float* Xk = (const float*)d_in[1];
  const float* Xv = (const float*)d_in[2];
  const float* Mk = (const float*)d_in[3];
  const float* Wq = (const float*)d_in[4];
  const float* Wk = (const float*)d_in[5];
  const float* Wv = (const float*)d_in[6];
  const float* Wo = (const float*)d_in[7];

  // ws layout (u16 units), total 56 MB:
  //  [0,1M)=WtQ [1M,2M)=WtK [2M,3M)=WtV [3M,4M)=WtO
  //  [4M,12M)=Qb  [12M,20M)=Kb  [20M,28M)=Vt
  //  aliases: Ctx(bf16,16MB)<-Qb after attn; O(f32,32MB)<-Kb+Vt after ctx GEMM
  u16* ws  = (u16*)d_ws;
  const size_t M = 1u << 20;
  u16* WtQ = ws;
  u16* WtK = ws + 1 * M;
  u16* WtV = ws + 2 * M;
  u16* WtO = ws + 3 * M;
  u16* Qb  = ws + 4 * M;       // [b,h,s,d] bf16
  u16* Kb  = ws + 12 * M;      // [b,h,s,d] bf16
  u16* Vt  = ws + 20 * M;      // [b,h,d,s] bf16
  u16* Ctx = Qb;               // [b,s,(h,d)] bf16 (Qb dead after attn)
  float* O = (float*)(ws + 12 * M);  // fp32 (Kb,Vt dead after ctx GEMM)

  float* out = (float*)d_out;                            // [b,s,f] fp32
  float* P   = out + (size_t)BATCH * SEQ * FDIM;         // attn probs fp32

  // weight transposes + bf16 convert: Wt[n][k] = W[k][n]
  transpose_k<<<dim3(16, 16, 1), 256, 0, stream>>>(Wq, WtQ, FDIM, FDIM);
  transpose_k<<<dim3(16, 16, 1), 256, 0, stream>>>(Wk, WtK, FDIM, FDIM);
  transpose_k<<<dim3(16, 16, 1), 256, 0, stream>>>(Wv, WtV, FDIM, FDIM);
  transpose_k<<<dim3(16, 16, 1), 256, 0, stream>>>(Wo, WtO, FDIM, FDIM);
  // projections (A fp32 converted in staging)
  gemm_bt<2, 2, 2, 4, 4><<<dim3(8, 64, 1), 256, 0, stream>>>(Xq, WtQ, Qb, FDIM, FDIM, FDIM, 0, 0, 0);
  gemm_bt<2, 2, 2, 4, 4><<<dim3(8, 64, 1), 256, 0, stream>>>(Xk, WtK, Kb, FDIM, FDIM, FDIM, 0, 0, 0);
  gemm_bt<3, 2, 2, 4, 4><<<dim3(8, 64, 1), 256, 0, stream>>>(Xv, WtV, Vt, FDIM, FDIM, FDIM, 0, 0, 0);
  // scores + softmax -> P (fp32, d_out attn region)
  attn_kernel<<<dim3(SEQ / 64, NHEAD, BATCH), 256, 0, stream>>>(Qb, Kb, Mk, P);
  // context = P @ Vt^T -> Ctx bf16 [b,s,(h,d)]  (A = fp32 P, converted in staging)
  gemm_bt<0, 4, 1, 2, 4><<<dim3(1, 8, BATCH * NHEAD), 256, 0, stream>>>(
      P, Vt, Ctx, SEQ, SEQ, SEQ, FDIM, (long)SEQ * SEQ, (long)DHEAD * SEQ);
  // out projection -> O (fp32)
  gemm_bt<1, 2, 2, 4, 4><<<dim3(8, 64, 1), 256, 0, stream>>>(Ctx, WtO, O, FDIM, FDIM, FDIM, FDIM, 0, 0);
  // residual + LayerNorm -> out (fp32)
  ln_kernel<<<dim3(BATCH * SEQ, 1, 1), 256, 0, stream>>>(O, Xq, out);
}